// Round 8
// baseline (428.161 us; speedup 1.0000x reference)
//
#include <hip/hip_runtime.h>
#include <stdint.h>

typedef unsigned short u16;
typedef __attribute__((ext_vector_type(8))) short    bf16x8;   // 8 bf16 in 4 VGPRs
typedef __attribute__((ext_vector_type(4))) float    f32x4;

// ---------- helpers ----------
__device__ __forceinline__ u16 f2bf(float f) {           // fp32 -> bf16, round-nearest-even
    unsigned u = __float_as_uint(f);
    u = (u + 0x7fffu + ((u >> 16) & 1u)) >> 16;
    return (u16)u;
}

__device__ __forceinline__ void gload16(const u16* src, u16* dst) {
    __builtin_amdgcn_global_load_lds((const __attribute__((address_space(1))) void*)src,
                                     (__attribute__((address_space(3))) void*)dst,
                                     16, 0, 0);
}

template <int IMM>
__device__ __forceinline__ bf16x8 dsr128(uint32_t addr) {
    bf16x8 r;
    asm volatile("ds_read_b128 %0, %1 offset:%2" : "=v"(r) : "v"(addr), "i"(IMM));
    return r;
}

#define LA(ARR) ((uint32_t)(uintptr_t)(__attribute__((address_space(3))) void*)&(ARR)[0])

// ---------- fused fp32 -> bf16 cast: x (12288 blocks) + Wq|Wk|Wv (1728 blocks) ----------
__global__ __launch_bounds__(256) void cast_all_kernel(const float* __restrict__ x,
                                                       const float* __restrict__ w0,
                                                       const float* __restrict__ w1,
                                                       const float* __restrict__ w2,
                                                       u16* __restrict__ xb,
                                                       u16* __restrict__ wb) {
    const int b = blockIdx.x;
    if (b < 12288) {                                  // x: 3145728 float4
        int i = b * 256 + threadIdx.x;
        float4 f = ((const float4*)x)[i];
        ushort4 o;
        o.x = f2bf(f.x); o.y = f2bf(f.y); o.z = f2bf(f.z); o.w = f2bf(f.w);
        ((ushort4*)xb)[i] = o;
    } else {                                          // W: 3 x 576 blocks of 256 float4
        const int i2 = b - 12288;
        const int w  = i2 / 576;                      // 0..2
        const int blk = i2 - w * 576;
        const float* src = (w == 0) ? w0 : (w == 1) ? w1 : w2;
        int i = blk * 256 + threadIdx.x;              // 576*256 = 147456 = 768*768/4
        float4 f = ((const float4*)src)[i];
        ushort4 o;
        o.x = f2bf(f.x); o.y = f2bf(f.y); o.z = f2bf(f.z); o.w = f2bf(f.w);
        ((ushort4*)wb)[(size_t)w * 147456 + i] = o;
    }
}

// ---------- bf16 32x32-tiled transpose: Vt[b][e][s] = V[b][s][e] (ld_in=2304) ----------
// also zeroes the rowsum buffer (it aliases the dead weight buffer; runs after proj GEMM)
__global__ __launch_bounds__(256) void transpose_bf16_kernel(const u16* __restrict__ V,
                                                             u16* __restrict__ Vt,
                                                             float* __restrict__ rsum) {
    __shared__ u16 tile[32][33];
    const int t = threadIdx.x;
    if (blockIdx.x == 0 && blockIdx.z == 0) {
        int idx = blockIdx.y * 256 + t;
        if (idx < 16384) rsum[idx] = 0.f;
    }
    const size_t z = blockIdx.z;
    const u16* Vb  = V  + z * (size_t)4096 * 2304;
    u16*       Vtb = Vt + z * (size_t)768 * 4096;
    const int c0 = blockIdx.x * 32;           // D (col) tile
    const int r0 = blockIdx.y * 32;           // S (row) tile
    const int lr = t >> 3;                    // 0..31
    const int lc = (t & 7) * 4;               // 0..28
    ushort4 in = *(const ushort4*)&Vb[(size_t)(r0 + lr) * 2304 + c0 + lc];
    tile[lr][lc + 0] = in.x; tile[lr][lc + 1] = in.y;
    tile[lr][lc + 2] = in.z; tile[lr][lc + 3] = in.w;
    __syncthreads();
    ushort4 o;
    o.x = tile[lc + 0][lr]; o.y = tile[lc + 1][lr];
    o.z = tile[lc + 2][lr]; o.w = tile[lc + 3][lr];
    *(ushort4*)&Vtb[(size_t)(c0 + lr) * 4096 + r0 + lc] = o;
}

// ---------- 2-phase GEMM (proj + QK; proven) ----------
template <int EPI, int WN, int NBX, int GRP, int NGRID, int NBY, int MINW>
__global__ __launch_bounds__(256, MINW) void gemm_bt_kernel(
        const u16* __restrict__ A, const u16* __restrict__ B, void* __restrict__ Cv,
        const float* __restrict__ b0, const float* __restrict__ b1, const float* __restrict__ b2,
        float* __restrict__ rs, float s2, int K,
        int lda, int ldb, int ldc, long batchA, long batchB, long batchC) {
    __shared__ __align__(16) u16 As[128 * 64];
    __shared__ __align__(16) u16 Bs[32 * WN * 64];

    constexpr int SPX = NGRID / (8 * NBX);        // strips per XCD
    const int lin = blockIdx.x;
    const int c = lin & 7, p = lin >> 3;
    const int bxi = p % GRP;
    const int rest = p / GRP;
    const int s = rest % SPX;
    const int g = rest / SPX;
    const int bx = g * GRP + bxi;
    const int strip = c * SPX + s;
    const int by = strip % NBY;
    const int bz = strip / NBY;

    const int t = threadIdx.x;
    const long z = bz;
    const u16* Ab = A + z * batchA + (long)by * 128 * lda;
    const u16* Bb = B + z * batchB + (long)bx * (32 * WN) * ldb;

    const int lane = t & 63;
    const int wave = t >> 6;
    const int wm = wave >> 1, wn = wave & 1;      // 2x2 wave grid
    const int quad = lane >> 4;
    const int frow = lane & 15;
    const int cc0 = quad ^ (frow & 7);            // swizzled chunk col for k-chunk 0

    f32x4 acc[4][WN];
#pragma unroll
    for (int i = 0; i < 4; i++)
#pragma unroll
        for (int j = 0; j < WN; j++)
#pragma unroll
            for (int e = 0; e < 4; e++) acc[i][j][e] = 0.f;

    int srow[WN], scol[WN];
#pragma unroll
    for (int j = 0; j < WN; j++) {
        const int d = t + j * 256;
        srow[j] = d >> 3;
        scol[j] = ((d & 7) ^ (srow[j] & 7)) * 8;
    }

    bf16x8 ra[4], rb[WN];
#pragma unroll
    for (int j = 0; j < 4; j++)
        ra[j] = *(const bf16x8*)(Ab + (long)srow[j] * lda + scol[j]);
#pragma unroll
    for (int j = 0; j < WN; j++)
        rb[j] = *(const bf16x8*)(Bb + (long)srow[j] * ldb + scol[j]);

    for (int kt = 0; kt < K; kt += 64) {
#pragma unroll
        for (int j = 0; j < 4; j++)
            *(bf16x8*)&As[(t + j * 256) * 8] = ra[j];
#pragma unroll
        for (int j = 0; j < WN; j++)
            *(bf16x8*)&Bs[(t + j * 256) * 8] = rb[j];
        __syncthreads();

        if (kt + 64 < K) {
            const int kn = kt + 64;
#pragma unroll
            for (int j = 0; j < 4; j++)
                ra[j] = *(const bf16x8*)(Ab + (long)srow[j] * lda + kn + scol[j]);
#pragma unroll
            for (int j = 0; j < WN; j++)
                rb[j] = *(const bf16x8*)(Bb + (long)srow[j] * ldb + kn + scol[j]);
        }

#pragma unroll
        for (int kk = 0; kk < 2; kk++) {
            const int cc = (cc0 ^ (kk * 4)) * 8;
            bf16x8 bfr[WN];
#pragma unroll
            for (int j = 0; j < WN; j++)
                bfr[j] = *(const bf16x8*)&Bs[(wn * WN * 16 + j * 16 + frow) * 64 + cc];
#pragma unroll
            for (int i = 0; i < 4; i++) {
                bf16x8 af = *(const bf16x8*)&As[(wm * 64 + i * 16 + frow) * 64 + cc];
#pragma unroll
                for (int j = 0; j < WN; j++)
                    acc[i][j] = __builtin_amdgcn_mfma_f32_16x16x32_bf16(af, bfr[j], acc[i][j], 0, 0, 0);
            }
        }
        __syncthreads();
    }

    const int m_base = by * 128 + wm * 64;
    const int n_base = bx * (32 * WN) + wn * (16 * WN);

    if (EPI == 0) {
        const int seg = n_base / 768;
        const float* bp = (seg == 0) ? b0 : (seg == 1) ? b1 : b2;
        u16* C = (u16*)Cv + z * batchC;
#pragma unroll
        for (int j = 0; j < WN; j++) {
            const int col = n_base + j * 16 + frow;
            const float bb = bp[col - seg * 768];
#pragma unroll
            for (int i = 0; i < 4; i++) {
                const int row0 = m_base + i * 16 + quad * 4;
#pragma unroll
                for (int r = 0; r < 4; r++)
                    C[(long)(row0 + r) * ldc + col] = f2bf(acc[i][j][r] + bb);
            }
        }
    } else if (EPI == 1) {
        u16* C = (u16*)Cv + z * batchC;
        float rowpart[4][4];
#pragma unroll
        for (int i = 0; i < 4; i++)
#pragma unroll
            for (int r = 0; r < 4; r++) rowpart[i][r] = 0.f;
#pragma unroll
        for (int i = 0; i < 4; i++) {
            const int row0 = m_base + i * 16 + quad * 4;
#pragma unroll
            for (int j = 0; j < WN; j++) {
                const int col = n_base + j * 16 + frow;
#pragma unroll
                for (int r = 0; r < 4; r++) {
                    float e = exp2f(acc[i][j][r] * s2);
                    C[(long)(row0 + r) * ldc + col] = f2bf(e);
                    rowpart[i][r] += e;
                }
            }
        }
#pragma unroll
        for (int i = 0; i < 4; i++)
#pragma unroll
            for (int r = 0; r < 4; r++) {
                float v = rowpart[i][r];
                v += __shfl_xor(v, 1); v += __shfl_xor(v, 2);
                v += __shfl_xor(v, 4); v += __shfl_xor(v, 8);
                if (frow == 0)
                    atomicAdd(&rs[z * 4096 + m_base + i * 16 + quad * 4 + r], v);
            }
    } else {
        float* C = (float*)Cv + z * batchC;
#pragma unroll
        for (int i = 0; i < 4; i++) {
            const int row0 = m_base + i * 16 + quad * 4;
            float inv[4];
#pragma unroll
            for (int r = 0; r < 4; r++) inv[r] = 1.0f / rs[z * 4096 + row0 + r];
#pragma unroll
            for (int j = 0; j < WN; j++) {
                const int col = n_base + j * 16 + frow;
#pragma unroll
                for (int r = 0; r < 4; r++)
                    C[(long)(row0 + r) * ldc + col] = acc[i][j][r] * inv[r];
            }
        }
    }
}

// ==================== R8: PV GEMM, fat wave-tile + explicit sync (gemm_pv) ====================
// R7 closed the QK avenue (occupancy 2x -> slower; 64x64 wave tiles are LDS-read-bound:
// 32 FLOP/LDS-byte < ~43 balance point).  PV (K=4096, 64 K-tiles = m201's steady-state
// regime) gets wave-tile 128x64: 2 waves/block (128 thr), tile 128x128, A read by only
// 2 waves -> 25% less LDS read traffic; grid stays 768 = exactly 3 blk/CU (the 256-wide
// alternative gives 384 blocks = 1.5/CU tail, which eats the gain).
// LDS 32 KB single-copy: 4 sub-regions [128 rows x 32 k] As0/As1/Bs0/Bs1, R7's exact
// chunk layout: chunk (r,c) at line r>>1, slot (r&1)*4 + (c^((r>>1)&3)) -- staging map
// and fragment-read map both reused verbatim (R7 passed refcheck with them).
// Sync per half-K (R7-proven): vmcnt(8)[=other half + next stage in flight] / s_barrier /
// 12 asm ds_read_b128 / lgkmcnt(0)+sched_barrier (rule #18) / s_barrier / restage 8 loads /
// 32 MFMA.  Tail: vmcnt(0) (R6's silent-no-wait trap).  VGPR ~200 (acc 128) -> 2 w/SIMD.
template <int NBX, int NBY, int GRP, int NGRID>
__global__ __launch_bounds__(128, 2) void gemm_pv_kernel(
        const u16* __restrict__ A, const u16* __restrict__ B, float* __restrict__ C,
        const float* __restrict__ rs, int K,
        int lda, int ldb, int ldc, long batchA, long batchB, long batchC) {
    __shared__ __align__(16) u16 As0[4096];   // A rows 0..127, K-half 0 (32 k)
    __shared__ __align__(16) u16 As1[4096];   // A, K-half 1
    __shared__ __align__(16) u16 Bs0[4096];   // B rows 0..127, K-half 0
    __shared__ __align__(16) u16 Bs1[4096];   // B, K-half 1

    constexpr int SPX = NGRID / (8 * NBX);
    const int lin = blockIdx.x;
    const int c = lin & 7, p = lin >> 3;
    const int bxi = p % GRP;
    const int rest = p / GRP;
    const int s = rest % SPX;
    const int g = rest / SPX;
    const int bx = g * GRP + bxi;
    const int strip = c * SPX + s;
    const int by = strip % NBY;
    const int bz = strip / NBY;

    const int t = threadIdx.x;                 // 0..127 (2 waves)
    const int lane = t & 63;
    const int wn = t >> 6;                     // wave -> N-half (wave tile 128x64)
    const int quad = lane >> 4, frow = lane & 15;

    const u16* Ab = A + (long)bz * batchA + (long)by * 128 * lda;
    const u16* Bb = B + (long)bz * batchB + (long)bx * 128 * ldb;

    // fragment read offset (bytes, sub-region-relative) -- R7 map verbatim
    const uint32_t rdo2 = (uint32_t)(((frow >> 1) * 64
                        + ((frow & 1) * 4 + (quad ^ ((frow >> 1) & 3))) * 8) * 2);
    const uint32_t bofs = (uint32_t)(wn * 4096);   // wn*64 rows = 32 lines * 128 B

    f32x4 acc[8][4];
#pragma unroll
    for (int i = 0; i < 8; i++)
#pragma unroll
        for (int j = 0; j < 4; j++)
#pragma unroll
            for (int e = 0; e < 4; e++) acc[i][j][e] = 0.f;

    // stage one 128x32 sub-region (512 chunks): thread t -> chunks {t, t+128, t+256, t+384}
    // dest base wave-uniform (q*1024 + wave*512 u16); HW adds lane*16B -> chunk q*128+t.
    const int wbase = (t & 64) * 8;            // wave*512 u16
    auto SS = [&](u16* dst, const u16* gb, int ld_, int kofs) {
#pragma unroll
        for (int q = 0; q < 4; ++q) {
            const int dd = q * 128 + t;
            const int sr = ((dd >> 3) << 1) | ((dd >> 2) & 1);        // 0..127
            const int sc = ((dd & 3) ^ ((dd >> 3) & 3)) * 8;          // u16 col in K-half
            gload16(gb + (long)sr * ld_ + kofs + sc, dst + q * 1024 + wbase);
        }
    };

#define MFMA32(AF, BF)                                                           \
    __builtin_amdgcn_s_setprio(1);                                               \
    _Pragma("unroll")                                                            \
    for (int i = 0; i < 8; ++i)                                                  \
        _Pragma("unroll")                                                        \
        for (int j = 0; j < 4; ++j)                                              \
            acc[i][j] = __builtin_amdgcn_mfma_f32_16x16x32_bf16(                 \
                AF[i], BF[j], acc[i][j], 0, 0, 0);                               \
    __builtin_amdgcn_s_setprio(0);

    // prologue: stage tile 0 (S0 older, S1 newer; 8 loads each)
    SS(As0, Ab, lda, 0);  SS(Bs0, Bb, ldb, 0);
    SS(As1, Ab, lda, 32); SS(Bs1, Bb, ldb, 32);

    for (int kt = 0; kt < K; kt += 64) {
        const bool pre = (kt + 64 < K);
        bf16x8 af[8], bf[4];

        // ---- P0: kk0 on As0/Bs0 ----
        asm volatile("s_waitcnt vmcnt(8)" ::: "memory");   // S0(t) landed
        __builtin_amdgcn_s_barrier();
        {
            const uint32_t aA = LA(As0) + rdo2;
            const uint32_t aB = LA(Bs0) + bofs + rdo2;
            af[0] = dsr128<0>(aA);    af[1] = dsr128<1024>(aA);
            af[2] = dsr128<2048>(aA); af[3] = dsr128<3072>(aA);
            af[4] = dsr128<4096>(aA); af[5] = dsr128<5120>(aA);
            af[6] = dsr128<6144>(aA); af[7] = dsr128<7168>(aA);
            bf[0] = dsr128<0>(aB);    bf[1] = dsr128<1024>(aB);
            bf[2] = dsr128<2048>(aB); bf[3] = dsr128<3072>(aB);
        }
        asm volatile("s_waitcnt lgkmcnt(0)" ::: "memory");
        __builtin_amdgcn_sched_barrier(0);
        __builtin_amdgcn_s_barrier();                      // all kk0 readers retired
        if (pre) { SS(As0, Ab, lda, kt + 64); SS(Bs0, Bb, ldb, kt + 64); }
        __builtin_amdgcn_sched_barrier(0);
        MFMA32(af, bf)

        // ---- P1: kk1 on As1/Bs1 ----
        if (pre) asm volatile("s_waitcnt vmcnt(8)" ::: "memory");  // S1(t) landed
        else     asm volatile("s_waitcnt vmcnt(0)" ::: "memory");  // tail: only 8 left
        __builtin_amdgcn_s_barrier();
        {
            const uint32_t aA = LA(As1) + rdo2;
            const uint32_t aB = LA(Bs1) + bofs + rdo2;
            af[0] = dsr128<0>(aA);    af[1] = dsr128<1024>(aA);
            af[2] = dsr128<2048>(aA); af[3] = dsr128<3072>(aA);
            af[4] = dsr128<4096>(aA); af[5] = dsr128<5120>(aA);
            af[6] = dsr128<6144>(aA); af[7] = dsr128<7168>(aA);
            bf[0] = dsr128<0>(aB);    bf[1] = dsr128<1024>(aB);
            bf[2] = dsr128<2048>(aB); bf[3] = dsr128<3072>(aB);
        }
        asm volatile("s_waitcnt lgkmcnt(0)" ::: "memory");
        __builtin_amdgcn_sched_barrier(0);
        __builtin_amdgcn_s_barrier();                      // all kk1 readers retired
        if (pre) { SS(As1, Ab, lda, kt + 96); SS(Bs1, Bb, ldb, kt + 96); }
        __builtin_amdgcn_sched_barrier(0);
        MFMA32(af, bf)
    }
#undef MFMA32

    // epilogue: O = acc / rowsum  (C/D: col = frow, row = quad*4 + r)
    const int m_base = by * 128;
    const int n_base = bx * 128 + wn * 64;
    const long z = bz;
    float* Cb = C + z * batchC;
    const float* rz = rs + z * 4096;
#pragma unroll
    for (int i = 0; i < 8; ++i) {
        const int row0 = m_base + i * 16 + quad * 4;
        float inv[4];
#pragma unroll
        for (int r = 0; r < 4; ++r) inv[r] = 1.0f / rz[row0 + r];
#pragma unroll
        for (int j = 0; j < 4; ++j) {
            const int col = n_base + j * 16 + frow;
#pragma unroll
            for (int r = 0; r < 4; ++r)
                Cb[(long)(row0 + r) * ldc + col] = acc[i][j][r] * inv[r];
        }
    }
}

extern "C" void kernel_launch(void* const* d_in, const int* in_sizes, int n_in,
                              void* d_out, int out_size, void* d_ws, size_t ws_size,
                              hipStream_t stream) {
    const float* x  = (const float*)d_in[0];
    const float* Wq = (const float*)d_in[1];
    const float* bq = (const float*)d_in[2];
    const float* Wk = (const float*)d_in[3];
    const float* bk = (const float*)d_in[4];
    const float* Wv = (const float*)d_in[5];
    const float* bv = (const float*)d_in[6];
    float* out = (float*)d_out;

    // B=4, S=4096, D=768; 16384 tokens. Workspace layout (total 238,419,968 B):
    //  @0          : xb bf16 [16384][768]      (25,165,824)  -- dead after proj; Vt reuses it
    //  @25,165,824 : QKV bf16 [16384][2304]    (75,497,472)
    //  @100,663,296: E bf16 [4][4096][4096]    (134,217,728)
    //  @234,881,024: Wqkv bf16 [2304][768]     (3,538,944)   -- dead after proj;
    //                 rowsum fp32[16384] (65,536) aliases its head, zeroed in transpose
    uint8_t* ws = (uint8_t*)d_ws;
    u16*   xb   = (u16*)(ws + 0);
    u16*   Vt   = (u16*)(ws + 0);
    u16*   QKV  = (u16*)(ws + 25165824);
    u16*   E    = (u16*)(ws + 100663296);
    u16*   Wqkv = (u16*)(ws + 234881024);
    float* rsum = (float*)(ws + 234881024);

    // 1) casts (x + all three W) in one launch: 12288 + 3*576 = 14016 blocks
    cast_all_kernel<<<14016, 256, 0, stream>>>(x, Wq, Wk, Wv, xb, Wqkv);

    // 2) fused QKV projection: [16384,768] x [2304,768]^T + bias -> QKV bf16 (ldc 2304)
    gemm_bt_kernel<0, 4, 18, 6, 2304, 128, 3><<<2304, 256, 0, stream>>>(
        xb, Wqkv, QKV, bq, bk, bv, nullptr, 0.f, 768, 768, 768, 2304, 0, 0, 0);

    // 3) V transpose per batch (V = QKV cols [1536,2304), ld 2304) -> Vt[e][s]; zero rowsum
    transpose_bf16_kernel<<<dim3(24, 128, 4), 256, 0, stream>>>(QKV + 1536, Vt, rsum);

    // 4) E = exp(scale * Q K^T) (per batch, 4096x4096, K=768) + rowsum atomics
    //    proven FAT 2-phase tile 128x256 (R0: 135 us); s2 = (1/sqrt(768)) * log2(e)
    gemm_bt_kernel<1, 8, 16, 4, 2048, 32, 2><<<2048, 256, 0, stream>>>(
        QKV, QKV + 768, E, nullptr, nullptr, nullptr, rsum, 0.05205954822032348f,
        768, 2304, 2304, 4096, (long)4096 * 2304, (long)4096 * 2304, (long)4096 * 4096);

    // 5) O = (E Vt^T) / rowsum -> fp32 out (per batch, M=4096, N=768, K=4096)
    //    NEW: 2-wave 128x128 tile (wave 128x64), explicit-sync pipeline; 768 blocks = 3/CU
    gemm_pv_kernel<6, 32, 6, 768><<<768, 128, 0, stream>>>(
        E, Vt, out, rsum, 4096,
        4096, 4096, 768, (long)4096 * 4096, (long)768 * 4096, (long)4096 * 768);
}